// Round 7
// baseline (141.264 us; speedup 1.0000x reference)
//
#include <hip/hip_runtime.h>
#include <cmath>

#define R_LEVELS 16
#define N_TAB    524288u
#define N_MASK   (N_TAB - 1u)
#define PRIME_H  2654435761u
#define M_PTS    1048576
#define BDIM     128              // buckets per axis
#define NBUCK    (BDIM * BDIM)    // 16384 Morton buckets
#define SBLK     64               // sort blocks
#define STHR     1024
#define SPB      (M_PTS / SBLK)   // 16384 (fits u16)
#define SITER    (SPB / STHR)     // 16
#define NFRAG    384              // 6 (layer,kc) x 64 lanes

typedef __attribute__((ext_vector_type(8)))  short bf16x8;
typedef __attribute__((ext_vector_type(16))) float f32x16;

union FragU { bf16x8 v; uint4 q; unsigned u[4]; unsigned short s[8]; };

struct ResArr { float r[R_LEVELS]; };

// pack_hi(f0,f1): u32 = [f0.top16 | f1.top16<<16]  (bf16 by truncation) -- f0 low
__device__ __forceinline__ unsigned pack_hi(float f0, float f1) {
    return __builtin_amdgcn_perm(__float_as_uint(f1), __float_as_uint(f0), 0x07060302u);
}
// pack_lo(f0,f1): bf16(residuals) packed RTN, f0 low
__device__ __forceinline__ unsigned pack_lo(float f0, float f1) {
    const float l0 = f0 - __uint_as_float(__float_as_uint(f0) & 0xffff0000u);
    const float l1 = f1 - __uint_as_float(__float_as_uint(f1) & 0xffff0000u);
    unsigned r;
    asm("v_cvt_pk_bf16_f32 %0, %1, %2" : "=v"(r) : "v"(l0), "v"(l1));
    return r;
}

__device__ __forceinline__ unsigned bucket_of(float x, float y) {
    unsigned bx = (unsigned)(x * (float)BDIM); if (bx >= BDIM) bx = BDIM - 1;
    unsigned by = (unsigned)(y * (float)BDIM); if (by >= BDIM) by = BDIM - 1;
    unsigned m = 0;
    #pragma unroll
    for (int i = 0; i < 7; ++i)
        m |= (((bx >> i) & 1u) << (2 * i)) | (((by >> i) & 1u) << (2 * i + 1));
    return m;
}

__global__ __launch_bounds__(STHR) void hist_k(const float2* __restrict__ coords,
                                               unsigned short* __restrict__ C) {
    __shared__ unsigned h[NBUCK];
    const int t = threadIdx.x;
    const int w = blockIdx.x;
    #pragma unroll
    for (int i = t; i < NBUCK; i += STHR) h[i] = 0u;
    __syncthreads();
    #pragma unroll
    for (int k = 0; k < SITER; ++k) {
        const int p = w * SPB + k * STHR + t;
        const float2 c = coords[p];
        atomicAdd(&h[bucket_of(c.x, c.y)], 1u);
    }
    __syncthreads();
    #pragma unroll
    for (int i = t; i < NBUCK; i += STHR)
        C[(size_t)w * NBUCK + i] = (unsigned short)h[i];
}

__global__ __launch_bounds__(256) void scanw_k(unsigned short* __restrict__ C,
                                               unsigned* __restrict__ T) {
    const int b = blockIdx.x * 256 + threadIdx.x;
    unsigned s = 0;
    for (int w = 0; w < SBLK; ++w) {
        const size_t i = (size_t)w * NBUCK + b;
        const unsigned v = C[i];
        C[i] = (unsigned short)s;
        s += v;
    }
    T[b] = s;
}

__global__ __launch_bounds__(256) void scan_k(const unsigned* __restrict__ T,
                                              unsigned* __restrict__ B) {
    __shared__ unsigned part[256];
    const int t = threadIdx.x;
    unsigned sum = 0;
    for (int k = 0; k < 64; ++k) sum += T[t * 64 + k];
    part[t] = sum;
    __syncthreads();
    for (int off = 1; off < 256; off <<= 1) {
        const unsigned v = (t >= off) ? part[t - off] : 0u;
        __syncthreads();
        part[t] += v;
        __syncthreads();
    }
    unsigned run = (t > 0) ? part[t - 1] : 0u;
    for (int k = 0; k < 64; ++k) {
        B[t * 64 + k] = run;
        run += T[t * 64 + k];
    }
}

__global__ __launch_bounds__(STHR) void scatter_k(const float2* __restrict__ coords,
                                                  const unsigned short* __restrict__ C,
                                                  const unsigned* __restrict__ B,
                                                  float2* __restrict__ sxy,
                                                  unsigned* __restrict__ sidx) {
    __shared__ unsigned off[NBUCK];
    const int t = threadIdx.x;
    const int w = blockIdx.x;
    #pragma unroll
    for (int i = t; i < NBUCK; i += STHR)
        off[i] = B[i] + (unsigned)C[(size_t)w * NBUCK + i];
    __syncthreads();
    #pragma unroll
    for (int k = 0; k < SITER; ++k) {
        const int p = w * SPB + k * STHR + t;
        const float2 c = coords[p];
        const unsigned b = bucket_of(c.x, c.y);
        const unsigned pos = atomicAdd(&off[b], 1u);
        sxy[pos] = c;
        sidx[pos] = (unsigned)p;
    }
}

// Precompute bf16 hi/lo weight fragments + zero-padded b2 + res table.
__global__ __launch_bounds__(64) void wprep_k(const float* __restrict__ W0,
                                              const float* __restrict__ W1,
                                              const float* __restrict__ W2,
                                              const float* __restrict__ b2,
                                              uint4* __restrict__ wbuf,
                                              float* __restrict__ b2p,
                                              float* __restrict__ restab,
                                              ResArr res) {
    const int lane = threadIdx.x;
    const int l31 = lane & 31;
    const int h   = lane >> 5;
    const float* Ws[3] = {W0, W1, W2};
    const int ncols[3] = {32, 32, 3};
    for (int l = 0; l < 3; ++l) {
        for (int kc = 0; kc < 2; ++kc) {
            FragU H, L;
            for (int e = 0; e < 8; ++e) {
                const int k = kc*16 + (e>>2)*8 + h*4 + (e&3);
                const float w = (l31 < ncols[l]) ? Ws[l][k*ncols[l] + l31] : 0.f;
                const unsigned short hi = (unsigned short)(__float_as_uint(w) >> 16);
                const float rem = w - __uint_as_float((unsigned)hi << 16);
                const unsigned u = __float_as_uint(rem);
                const unsigned short lo = (unsigned short)((u + 0x7fffu + ((u >> 16) & 1u)) >> 16);
                H.s[e] = hi;
                L.s[e] = lo;
            }
            const int fi = (l*2 + kc)*64 + lane;
            wbuf[fi]         = H.q;
            wbuf[NFRAG + fi] = L.q;
        }
    }
    if (lane < 32) b2p[lane] = (lane < 3) ? b2[lane] : 0.f;
    if (lane < R_LEVELS) restab[lane] = res.r[lane];
}

__global__ __launch_bounds__(256) void ngp_mfma(
    const float2* __restrict__ pts,      // sorted coords (or raw)
    const unsigned* __restrict__ sidx,   // permutation, or nullptr
    const float* __restrict__ hashf,
    const uint4* __restrict__ wbuf,
    const float* __restrict__ b0,
    const float* __restrict__ b1,
    const float* __restrict__ b2p,
    const float* __restrict__ restab,
    float* __restrict__ out)
{
    const unsigned nwg = gridDim.x;
    const unsigned chunk = nwg >> 3;
    const unsigned sb = (blockIdx.x & 7u) * chunk + (blockIdx.x >> 3);
    const int tid  = threadIdx.x;
    const int lane = tid & 63;
    const int wv   = tid >> 6;
    const int l31  = lane & 31;
    const int h    = lane >> 5;
    const int base = (int)(sb * 256u) + wv * 64;
    const int pA   = base + l31;
    const int pB   = base + 32 + l31;

    const float2 cA = pts[pA];
    const float2 cB = pts[pB];

    // res pairs for this lane's level set: levels 4c+2h+{0,1}, c=0..3
    float2 resp[4];
    #pragma unroll
    for (int c = 0; c < 4; ++c)
        resp[c] = *(const float2*)&restab[4*c + 2*h];

    // interp 4 levels (half = kc) of point cc -> one hi/lo fragment pair
    auto interp_half = [&](float2 cc, int half, FragU& H, FragU& L) {
        float2 v00[4], v01[4], v10[4], v11[4];
        float wxs[4], wys[4];
        #pragma unroll
        for (int q = 0; q < 4; ++q) {           // q = 2*(c&1)+d
            const int c = 2*half + (q>>1);
            const int d = q & 1;
            const int lvi = 4*c + 2*h + d;
            const float rr = d ? resp[c].y : resp[c].x;
            const float x = cc.x * rr;
            const float y = cc.y * rr;
            const float xf = floorf(x);
            const float yf = floorf(y);
            wxs[q] = x - xf;
            wys[q] = y - yf;
            const unsigned x0 = (unsigned)xf;
            const unsigned y0 = (unsigned)yf;
            const unsigned hy0 = PRIME_H * y0;
            const unsigned hy1 = PRIME_H * (y0 + 1u);
            const unsigned i00 = (x0 ^ hy0) & N_MASK;
            const unsigned i01 = (x0 ^ hy1) & N_MASK;
            const unsigned i10 = ((x0 + 1u) ^ hy0) & N_MASK;
            const unsigned i11 = ((x0 + 1u) ^ hy1) & N_MASK;
            const float2* tab = (const float2*)hashf + ((size_t)lvi << 19);
            v00[q] = tab[i00];
            v01[q] = tab[i01];
            v10[q] = tab[i10];
            v11[q] = tab[i11];
        }
        #pragma unroll
        for (int q = 0; q < 4; ++q) {
            const float wx = wxs[q], wy = wys[q];
            const float w00 = (1.f - wx) * (1.f - wy);
            const float w01 = (1.f - wx) * wy;
            const float w10 = wx * (1.f - wy);
            const float w11 = wx * wy;
            const float f0 = v00[q].x*w00 + v01[q].x*w01 + v10[q].x*w10 + v11[q].x*w11;
            const float f1 = v00[q].y*w00 + v01[q].y*w01 + v10[q].y*w10 + v11[q].y*w11;
            H.u[q] = pack_hi(f0, f1);
            L.u[q] = pack_lo(f0, f1);
        }
    };

    // a[4q'+j] = b[8q' + 4h + j]
    auto bias_init = [&](const float* b) -> f32x16 {
        f32x16 a;
        #pragma unroll
        for (int q = 0; q < 4; ++q) {
            const float4 t = *(const float4*)(b + 8*q + 4*h);
            a[4*q+0] = t.x; a[4*q+1] = t.y; a[4*q+2] = t.z; a[4*q+3] = t.w;
        }
        return a;
    };

    // X fragments live in registers the whole time
    FragU Ah0, Al0, Ah1, Al1;   // point batch tb0 (pA), kc0/kc1 hi/lo
    FragU Bh0, Bl0, Bh1, Bl1;   // point batch tb1 (pB)

    interp_half(cA, 0, Ah0, Al0);
    interp_half(cA, 1, Ah1, Al1);
    interp_half(cB, 0, Bh0, Bl0);
    interp_half(cB, 1, Bh1, Bl1);

    f32x16 a0, a1;

    auto layer = [&](int l, const float* b) {
        FragU wh0, wl0, wh1, wl1;
        wh0.q = wbuf[(l*2+0)*64 + lane];
        wl0.q = wbuf[NFRAG + (l*2+0)*64 + lane];
        wh1.q = wbuf[(l*2+1)*64 + lane];
        wl1.q = wbuf[NFRAG + (l*2+1)*64 + lane];
        f32x16 A0 = bias_init(b);
        f32x16 A1 = A0;
        A0 = __builtin_amdgcn_mfma_f32_32x32x16_bf16(wh0.v, Ah0.v, A0, 0, 0, 0);
        A0 = __builtin_amdgcn_mfma_f32_32x32x16_bf16(wh0.v, Al0.v, A0, 0, 0, 0);
        A0 = __builtin_amdgcn_mfma_f32_32x32x16_bf16(wl0.v, Ah0.v, A0, 0, 0, 0);
        A0 = __builtin_amdgcn_mfma_f32_32x32x16_bf16(wh1.v, Ah1.v, A0, 0, 0, 0);
        A0 = __builtin_amdgcn_mfma_f32_32x32x16_bf16(wh1.v, Al1.v, A0, 0, 0, 0);
        A0 = __builtin_amdgcn_mfma_f32_32x32x16_bf16(wl1.v, Ah1.v, A0, 0, 0, 0);
        A1 = __builtin_amdgcn_mfma_f32_32x32x16_bf16(wh0.v, Bh0.v, A1, 0, 0, 0);
        A1 = __builtin_amdgcn_mfma_f32_32x32x16_bf16(wh0.v, Bl0.v, A1, 0, 0, 0);
        A1 = __builtin_amdgcn_mfma_f32_32x32x16_bf16(wl0.v, Bh0.v, A1, 0, 0, 0);
        A1 = __builtin_amdgcn_mfma_f32_32x32x16_bf16(wh1.v, Bh1.v, A1, 0, 0, 0);
        A1 = __builtin_amdgcn_mfma_f32_32x32x16_bf16(wh1.v, Bl1.v, A1, 0, 0, 0);
        A1 = __builtin_amdgcn_mfma_f32_32x32x16_bf16(wl1.v, Bh1.v, A1, 0, 0, 0);
        a0 = A0; a1 = A1;
    };

    // leaky + hi/lo repack: D reg e -> B-frag(kc0) elem e; D reg 8+e -> B-frag(kc1) elem e
    auto act_repack = [&](const f32x16& a, FragU& xh0, FragU& xl0, FragU& xh1, FragU& xl1) {
        float v[16];
        #pragma unroll
        for (int r = 0; r < 16; ++r) v[r] = fmaxf(a[r], 0.01f * a[r]);
        #pragma unroll
        for (int w = 0; w < 4; ++w) {
            xh0.u[w] = pack_hi(v[2*w],   v[2*w+1]);
            xl0.u[w] = pack_lo(v[2*w],   v[2*w+1]);
            xh1.u[w] = pack_hi(v[8+2*w], v[8+2*w+1]);
            xl1.u[w] = pack_lo(v[8+2*w], v[8+2*w+1]);
        }
    };

    layer(0, b0);
    act_repack(a0, Ah0, Al0, Ah1, Al1);
    act_repack(a1, Bh0, Bl0, Bh1, Bl1);
    layer(1, b1);
    act_repack(a0, Ah0, Al0, Ah1, Al1);
    act_repack(a1, Bh0, Bl0, Bh1, Bl1);
    layer(2, b2p);

    if (h == 0) {
        const unsigned o0 = sidx ? sidx[pA] : (unsigned)pA;
        const unsigned o1 = sidx ? sidx[pB] : (unsigned)pB;
        out[(size_t)o0*3 + 0] = a0[0];
        out[(size_t)o0*3 + 1] = a0[1];
        out[(size_t)o0*3 + 2] = a0[2];
        out[(size_t)o1*3 + 0] = a1[0];
        out[(size_t)o1*3 + 1] = a1[1];
        out[(size_t)o1*3 + 2] = a1[2];
    }
}

extern "C" void kernel_launch(void* const* d_in, const int* in_sizes, int n_in,
                              void* d_out, int out_size, void* d_ws, size_t ws_size,
                              hipStream_t stream) {
    ResArr res;
    for (int i = 0; i < R_LEVELS; ++i)
        res.r[i] = (float)nearbyint(exp2(4.0 + (7.0 / 15.0) * (double)i));
    res.r[0] = 16.f;
    res.r[R_LEVELS - 1] = 2048.f;

    const float2* coords = (const float2*)d_in[0];
    const float* hashf   = (const float*)d_in[1];
    const float* W0      = (const float*)d_in[2];
    const float* b0      = (const float*)d_in[3];
    const float* W1      = (const float*)d_in[4];
    const float* b1      = (const float*)d_in[5];
    const float* W2      = (const float*)d_in[6];
    const float* b2      = (const float*)d_in[7];
    float* out           = (float*)d_out;

    // ws: C u16[64*16384] | T | B | sxy f2[M] | sidx u32[M] | wbuf | b2p | restab
    const size_t off_C      = 0;
    const size_t off_T      = off_C + (size_t)SBLK * NBUCK * 2;     // 2 MB
    const size_t off_B      = off_T + NBUCK * 4;
    const size_t off_sxy    = off_B + NBUCK * 4;
    const size_t off_sidx   = off_sxy + (size_t)M_PTS * sizeof(float2);
    const size_t off_wbuf   = off_sidx + (size_t)M_PTS * 4;
    const size_t off_b2p    = off_wbuf + 2 * NFRAG * sizeof(uint4);
    const size_t off_restab = off_b2p + 32 * sizeof(float);
    const size_t need       = off_restab + R_LEVELS * sizeof(float);
    const size_t need_min   = 2 * NFRAG * sizeof(uint4) + 32 * sizeof(float)
                              + R_LEVELS * sizeof(float);

    dim3 blockM(256);
    dim3 gridM(M_PTS / 256);

    if (ws_size >= need) {
        unsigned short* C = (unsigned short*)((char*)d_ws + off_C);
        unsigned* T    = (unsigned*)((char*)d_ws + off_T);
        unsigned* B    = (unsigned*)((char*)d_ws + off_B);
        float2*   sxy  = (float2*)((char*)d_ws + off_sxy);
        unsigned* sidx = (unsigned*)((char*)d_ws + off_sidx);
        uint4*    wbuf = (uint4*)((char*)d_ws + off_wbuf);
        float*    b2p  = (float*)((char*)d_ws + off_b2p);
        float*    rtab = (float*)((char*)d_ws + off_restab);

        hipLaunchKernelGGL(wprep_k,   dim3(1), dim3(64), 0, stream,
                           W0, W1, W2, b2, wbuf, b2p, rtab, res);
        hipLaunchKernelGGL(hist_k,    dim3(SBLK), dim3(STHR), 0, stream, coords, C);
        hipLaunchKernelGGL(scanw_k,   dim3(NBUCK / 256), dim3(256), 0, stream, C, T);
        hipLaunchKernelGGL(scan_k,    dim3(1), dim3(256), 0, stream, T, B);
        hipLaunchKernelGGL(scatter_k, dim3(SBLK), dim3(STHR), 0, stream, coords, C, B, sxy, sidx);
        hipLaunchKernelGGL(ngp_mfma,  gridM, blockM, 0, stream,
                           sxy, sidx, hashf, wbuf, b0, b1, b2p, rtab, out);
    } else if (ws_size >= need_min) {
        uint4* wbuf = (uint4*)d_ws;
        float* b2p  = (float*)((char*)d_ws + 2 * NFRAG * sizeof(uint4));
        float* rtab = b2p + 32;
        hipLaunchKernelGGL(wprep_k,   dim3(1), dim3(64), 0, stream,
                           W0, W1, W2, b2, wbuf, b2p, rtab, res);
        hipLaunchKernelGGL(ngp_mfma,  gridM, blockM, 0, stream,
                           coords, (const unsigned*)nullptr, hashf, wbuf, b0, b1, b2p, rtab, out);
    }
}